// Round 1
// 370.302 us; speedup vs baseline: 1.0519x; 1.0519x over previous
//
#include <hip/hip_runtime.h>
#include <hip/hip_bf16.h>

#define G_ 2048
#define NPG_ 128
#define INC_ 151
#define HID_ 64
#define NNODES_ (G_ * NPG_)      // 262144
#define NEDGES_ 2097152

typedef __hip_bfloat16 bf16;
typedef short bf16x8v __attribute__((ext_vector_type(8)));
typedef float f32x4 __attribute__((ext_vector_type(4)));

static __device__ __forceinline__ short f2bs(float f) {
    __hip_bfloat16 b = __float2bfloat16(f);
    return __builtin_bit_cast(short, b);
}
static __device__ __forceinline__ float b2f(short s) {
    unsigned int u = ((unsigned int)(unsigned short)s) << 16;
    return __builtin_bit_cast(float, u);
}

// ---------------------------------------------------------------------------
// k0C1 (fused): blocks 0..255 = coarse histogram (bucket = s>>10) into
// bccount[b][256]; blocks 256..297 = W1 [151][64] fp32 -> Bt [64][168] bf16.
// ---------------------------------------------------------------------------
__global__ void __launch_bounds__(256) k0C1(const float* __restrict__ W1,
                                            bf16* __restrict__ Bt,
                                            const int* __restrict__ ei,
                                            unsigned int* __restrict__ bccount) {
    __shared__ unsigned int hist[256];
    const int tid = threadIdx.x;
    if (blockIdx.x >= 256) {
        int i = (blockIdx.x - 256) * 256 + tid;
        if (i < 64 * 168) {
            int n = i / 168, k = i - n * 168;
            float v = (k < 151) ? W1[k * 64 + n] : 0.f;
            Bt[i] = __float2bfloat16(v);
        }
        return;
    }
    hist[tid] = 0;
    __syncthreads();
    const int e0 = blockIdx.x * 8192;
    for (int e = e0 + tid; e < e0 + 8192; e += 256)
        atomicAdd(&hist[ei[e] >> 10], 1u);
    __syncthreads();
    bccount[blockIdx.x * 256 + tid] = hist[tid];
}

// ---------------------------------------------------------------------------
// K1 (MFMA): h = x @ W1 bf16, as_[n]=h.att_src, ad_[n]=h.att_dst.
// ---------------------------------------------------------------------------
__global__ void __launch_bounds__(256) k1_mfma(
        const float* __restrict__ x, const bf16* __restrict__ Bt,
        const float* __restrict__ att_src, const float* __restrict__ att_dst,
        bf16* __restrict__ h, float* __restrict__ as_, float* __restrict__ ad_) {
    __shared__ __align__(16) bf16 Bs[64 * 168];
    const int tid = threadIdx.x;
    const int rowbase = blockIdx.x * 64;

    {
        const uint4* s = (const uint4*)Bt;
        uint4* d = (uint4*)Bs;
        for (int i = tid; i < 1344; i += 256) d[i] = s[i];
    }
    __syncthreads();

    const int wv = tid >> 6, lane = tid & 63;
    const int quad = lane >> 4, m = lane & 15;
    const int row = rowbase + wv * 16 + m;
    const float* xr = x + (size_t)row * 151;

    f32x4 acc[4];
#pragma unroll
    for (int t = 0; t < 4; t++) acc[t] = (f32x4){0.f, 0.f, 0.f, 0.f};

#pragma unroll
    for (int ks = 0; ks < 5; ks++) {
        const int k0 = ks * 32 + quad * 8;
        float a[8];
        if (ks < 4) {
#pragma unroll
            for (int e = 0; e < 8; e++) a[e] = xr[k0 + e];
        } else {
#pragma unroll
            for (int e = 0; e < 8; e++) {
                int c = k0 + e;
                a[e] = (c < 151) ? xr[c] : 0.f;
            }
        }
        bf16x8v af = {f2bs(a[0]), f2bs(a[1]), f2bs(a[2]), f2bs(a[3]),
                      f2bs(a[4]), f2bs(a[5]), f2bs(a[6]), f2bs(a[7])};
#pragma unroll
        for (int t = 0; t < 4; t++) {
            bf16x8v bfr = *(const bf16x8v*)&Bs[(t * 16 + m) * 168 + k0];
            acc[t] = __builtin_amdgcn_mfma_f32_16x16x32_bf16(af, bfr, acc[t], 0, 0, 0);
        }
    }

    float as4[4], ad4[4];
#pragma unroll
    for (int t = 0; t < 4; t++) {
        as4[t] = att_src[t * 16 + m];
        ad4[t] = att_dst[t * 16 + m];
    }
#pragma unroll
    for (int r = 0; r < 4; r++) {
        float s = acc[0][r] * as4[0] + acc[1][r] * as4[1] +
                  acc[2][r] * as4[2] + acc[3][r] * as4[3];
        float d = acc[0][r] * ad4[0] + acc[1][r] * ad4[1] +
                  acc[2][r] * ad4[2] + acc[3][r] * ad4[3];
#pragma unroll
        for (int off = 1; off <= 8; off <<= 1) {
            s += __shfl_xor(s, off);
            d += __shfl_xor(d, off);
        }
        const int node = rowbase + wv * 16 + quad * 4 + r;
        if (m == 0) { as_[node] = s; ad_[node] = d; }
#pragma unroll
        for (int t = 0; t < 4; t++) {
            float val = acc[t][r];
            float oth = __shfl_xor(val, 1);
            if (!(lane & 1)) {
                unsigned short lo = (unsigned short)f2bs(val);
                unsigned short hi = (unsigned short)f2bs(oth);
                unsigned int u = ((unsigned int)hi << 16) | lo;
                *(unsigned int*)&h[(size_t)node * 64 + t * 16 + m] = u;
            }
        }
    }
}

// ---------------------------------------------------------------------------
// kC2a: 256 blocks, one bucket column each. Exclusive scan of bccount[*][bk]
// over the 256 coarse blocks (in place); bucket total -> totals[bk].
// ---------------------------------------------------------------------------
__global__ void __launch_bounds__(256) kC2a(unsigned int* __restrict__ bccount,
                                            unsigned int* __restrict__ totals) {
    __shared__ unsigned int sc[256];
    const int tid = threadIdx.x, bk = blockIdx.x;
    unsigned int c = bccount[tid * 256 + bk];
    sc[tid] = c;
    __syncthreads();
    for (int off = 1; off < 256; off <<= 1) {
        unsigned int v = (tid >= off) ? sc[tid - off] : 0;
        __syncthreads();
        sc[tid] += v;
        __syncthreads();
    }
    bccount[tid * 256 + bk] = sc[tid] - c;   // exclusive over blocks
    if (tid == 255) totals[bk] = sc[255];
}

// ---------------------------------------------------------------------------
// kC2b: 1 tiny block. Exclusive scan of 256 bucket totals -> cbase;
// sentinels cbase[256]=E, base4[8192]=E.
// ---------------------------------------------------------------------------
__global__ void __launch_bounds__(256) kC2b(const unsigned int* __restrict__ totals,
                                            unsigned int* __restrict__ cbase,
                                            unsigned int* __restrict__ base4) {
    __shared__ unsigned int sc[256];
    const int tid = threadIdx.x;
    unsigned int c = totals[tid];
    sc[tid] = c;
    __syncthreads();
    for (int off = 1; off < 256; off <<= 1) {
        unsigned int v = (tid >= off) ? sc[tid - off] : 0;
        __syncthreads();
        sc[tid] += v;
        __syncthreads();
    }
    cbase[tid] = sc[tid] - c;
    if (tid == 255) {
        cbase[256] = sc[255];
        base4[G_ * 4] = NEDGES_;
    }
}

// ---------------------------------------------------------------------------
// kC3: scatter u32 records ((s&1023)<<7 | dl) to coarse buckets.
// rec bits: [16:14]=g&7, [13:7]=sl, [6:0]=dl.
// ---------------------------------------------------------------------------
__global__ void __launch_bounds__(256) kC3_scatter(const int* __restrict__ ei,
                                                   const unsigned int* __restrict__ bccount,
                                                   const unsigned int* __restrict__ cbase,
                                                   unsigned int* __restrict__ rbuf) {
    __shared__ unsigned int cur[256];
    const int tid = threadIdx.x;
    cur[tid] = cbase[tid] + bccount[blockIdx.x * 256 + tid];
    __syncthreads();
    const int e0 = blockIdx.x * 8192;
    for (int e = e0 + tid; e < e0 + 8192; e += 256) {
        int s = ei[e];
        int d = ei[NEDGES_ + e];
        int bk = s >> 10;
        unsigned int pos = atomicAdd(&cur[bk], 1u);
        rbuf[pos] = (((unsigned int)s & 1023u) << 7) | ((unsigned int)d & 127u);
    }
}

// ---------------------------------------------------------------------------
// kC4: per coarse bucket (8 graphs): 32 fine buckets = (g&7)*4 + (dl>>5).
// Counts -> base4[4g+p]; final eb u16 ((sl<<7)|dl) written in per-(graph,
// dst-quarter) contiguous runs. 5-bit ballot-aggregated LDS cursors.
// ---------------------------------------------------------------------------
__global__ void __launch_bounds__(256) kC4_fine(const unsigned int* __restrict__ rbuf,
                                                const unsigned int* __restrict__ cbase,
                                                unsigned int* __restrict__ base4,
                                                unsigned short* __restrict__ eb) {
    __shared__ unsigned int lcnt[32];
    __shared__ unsigned int cur[32];
    const int tid = threadIdx.x;
    const int b = blockIdx.x;
    const unsigned int s0 = cbase[b], s1 = cbase[b + 1];
    if (tid < 32) lcnt[tid] = 0;
    __syncthreads();
    for (unsigned int i = s0 + tid; i < s1; i += 256) {
        unsigned int rec = rbuf[i];
        int key = ((rec >> 12) & 0x1C) | ((rec >> 5) & 3);  // (g&7)*4 + quarter
        atomicAdd(&lcnt[key], 1u);
    }
    __syncthreads();
    if (tid == 0) {
        unsigned int r = 0;
#pragma unroll
        for (int j = 0; j < 32; j++) {
            base4[b * 32 + j] = s0 + r;
            cur[j] = s0 + r;
            r += lcnt[j];
        }
    }
    __syncthreads();
    const int lane = tid & 63;
    for (unsigned int i = s0 + tid; i < s1; i += 256) {
        unsigned int rec = rbuf[i];
        int key = ((rec >> 12) & 0x1C) | ((rec >> 5) & 3);
        unsigned long long m = __ballot(1);
#pragma unroll
        for (int bit = 0; bit < 5; bit++) {
            unsigned long long bb = __ballot((key >> bit) & 1);
            m &= ((key >> bit) & 1) ? bb : ~bb;
        }
        int leader = __builtin_ctzll(m);
        int rank = __builtin_popcountll(m & ((1ull << lane) - 1ull));
        unsigned int bp = 0;
        if (lane == leader)
            bp = atomicAdd(&cur[key], (unsigned int)__builtin_popcountll(m));
        bp = __shfl((int)bp, leader);
        eb[bp + rank] = (unsigned short)(rec & 0x3FFFu);
    }
}

// ---------------------------------------------------------------------------
// K3: one graph per block, MFMA. Edges now sorted by (g, dst-quarter):
// each pass p streams its exact contiguous eb range once, full lane util,
// no edge cache, no cap. Row sums fused into the S->bf16 convert.
// LDS 52736 B static (3 blocks/CU):
//   Ab  bf16 [128][136]  @0       (34816)
//   S   fp32 [32][128]   @34816   (16384)  per-pass exp accumulator
//   hT  bf16 [64][136]   @34816   (17408)  staged after build (union with S)
//   dinv fp32[128]       @52224   (512)
// ---------------------------------------------------------------------------
__global__ void __launch_bounds__(256) k3_graph(
        const unsigned short* __restrict__ eb, const unsigned int* __restrict__ base4,
        const bf16* __restrict__ h,
        const float* __restrict__ as_, const float* __restrict__ ad_,
        const float* __restrict__ b1, const float* __restrict__ Wlin,
        const float* __restrict__ blin, float* __restrict__ out) {
    __shared__ __align__(16) unsigned char lds[52736];
    short* Ab = (short*)lds;                               // [128][136]
    float* S = (float*)(lds + 34816);                      // [32][128]
    short* hT = (short*)(lds + 34816);                     // [64][136]
    float* dinv = (float*)(lds + 52224);                   // [128]

    const int tid = threadIdx.x;
    const int g = blockIdx.x;
    const float* asg = as_ + (g << 7);
    const float* adg = ad_ + (g << 7);
    const unsigned int* hgu = (const unsigned int*)(h + ((size_t)g << 13));

    // build A[dst][src] = exp(leakyrelu(alpha)) in 4 passes of 32 dst rows;
    // pass p reads only its pre-sorted edge range. Self-loops injected in-pass.
#pragma unroll 1
    for (int p = 0; p < 4; p++) {
        for (int i = tid; i < 1024; i += 256)
            ((float4*)S)[i] = make_float4(0.f, 0.f, 0.f, 0.f);
        __syncthreads();
        if (tid < 32) {
            int node = 32 * p + tid;
            float a = asg[node] + adg[node];
            a = (a > 0.f) ? a : 0.2f * a;
            atomicAdd(&S[(tid << 7) + node], __expf(a));
        }
        const unsigned int q0 = base4[(g << 2) + p];
        const unsigned int q1 = base4[(g << 2) + p + 1];
        for (unsigned int k = q0 + tid; k < q1; k += 256) {
            unsigned int v = eb[k];
            int sl = v >> 7, dl = v & 127;
            float a = asg[sl] + adg[dl];
            a = (a > 0.f) ? a : 0.2f * a;
            atomicAdd(&S[((dl & 31) << 7) + sl], __expf(a));
        }
        __syncthreads();
        // fused: convert S[32][128] -> Ab rows 32p.. (bf16, stride 136) AND
        // row sums. Thread covers 8 floats of a row; 16-lane shfl tree/row.
        float rs[2];
#pragma unroll
        for (int hf = 0; hf < 2; hf++) {
            int c = tid + (hf << 8);
            int r = c >> 4;
            int col = (c & 15) << 3;
            float4 v0 = ((const float4*)S)[c * 2];
            float4 v1 = ((const float4*)S)[c * 2 + 1];
            rs[hf] = v0.x + v0.y + v0.z + v0.w + v1.x + v1.y + v1.z + v1.w;
            bf16x8v pk = {f2bs(v0.x), f2bs(v0.y), f2bs(v0.z), f2bs(v0.w),
                          f2bs(v1.x), f2bs(v1.y), f2bs(v1.z), f2bs(v1.w)};
            *(bf16x8v*)&Ab[(32 * p + r) * 136 + col] = pk;
        }
#pragma unroll
        for (int off = 1; off <= 8; off <<= 1) {
            rs[0] += __shfl_xor(rs[0], off);
            rs[1] += __shfl_xor(rs[1], off);
        }
        if ((tid & 15) == 0) {
            dinv[32 * p + (tid >> 4)] = 1.f / rs[0];
            dinv[32 * p + 16 + (tid >> 4)] = 1.f / rs[1];
        }
        __syncthreads();
    }

    // stage hT[f][j] (transposed, stride 136) from h[j][f]
    for (int idx = tid; idx < 4096; idx += 256) {
        unsigned int u = hgu[idx];
        int j = idx >> 5, f2 = idx & 31;
        hT[(2 * f2) * 136 + j] = (short)(u & 0xFFFF);
        hT[(2 * f2 + 1) * 136 + j] = (short)(u >> 16);
    }
    __syncthreads();

    // MFMA: wave w -> rows i0=w*32 (2 M-tiles), 4 N-tiles, K=128 (4 steps)
    const int w = tid >> 6, lane = tid & 63;
    const int quad = lane >> 4, m = lane & 15;
    const int i0 = w * 32;
    f32x4 acc[2][4];
#pragma unroll
    for (int mt = 0; mt < 2; mt++)
#pragma unroll
        for (int nt = 0; nt < 4; nt++) acc[mt][nt] = (f32x4){0.f, 0.f, 0.f, 0.f};

#pragma unroll
    for (int ks = 0; ks < 4; ks++) {
        const int k0 = ks * 32 + quad * 8;
        bf16x8v a0 = *(const bf16x8v*)&Ab[(i0 + m) * 136 + k0];
        bf16x8v a1 = *(const bf16x8v*)&Ab[(i0 + 16 + m) * 136 + k0];
#pragma unroll
        for (int nt = 0; nt < 4; nt++) {
            bf16x8v bfr = *(const bf16x8v*)&hT[(nt * 16 + m) * 136 + k0];
            acc[0][nt] = __builtin_amdgcn_mfma_f32_16x16x32_bf16(a0, bfr, acc[0][nt], 0, 0, 0);
            acc[1][nt] = __builtin_amdgcn_mfma_f32_16x16x32_bf16(a1, bfr, acc[1][nt], 0, 0, 0);
        }
    }

    // epilogue: relu(acc*dinv + b1) . Wlin
    float dv[2][4];
#pragma unroll
    for (int mt = 0; mt < 2; mt++)
#pragma unroll
        for (int r = 0; r < 4; r++)
            dv[mt][r] = dinv[i0 + mt * 16 + quad * 4 + r];

    float p = 0.f;
#pragma unroll
    for (int nt = 0; nt < 4; nt++) {
        float bb = b1[nt * 16 + m];
#pragma unroll
        for (int mt = 0; mt < 2; mt++) {
#pragma unroll
            for (int r = 0; r < 4; r++) {
                int il = i0 + mt * 16 + quad * 4 + r;
                float v = acc[mt][nt][r] * dv[mt][r] + bb;
                v = v > 0.f ? v : 0.f;
                p += v * Wlin[il * 64 + nt * 16 + m];
            }
        }
    }
#pragma unroll
    for (int off = 32; off; off >>= 1) p += __shfl_xor(p, off);

    __syncthreads();
    if (lane == 0) S[w] = p;
    __syncthreads();
    if (tid == 0) {
        float logit = S[0] + S[1] + S[2] + S[3] + blin[0];
        out[g] = 1.f / (1.f + __expf(-logit));
    }
}

// ---------------------------------------------------------------------------
extern "C" void kernel_launch(void* const* d_in, const int* in_sizes, int n_in,
                              void* d_out, int out_size, void* d_ws, size_t ws_size,
                              hipStream_t stream) {
    (void)in_sizes; (void)n_in; (void)out_size; (void)ws_size;
    const float* x       = (const float*)d_in[0];
    const int*   ei      = (const int*)d_in[1];
    const float* W1      = (const float*)d_in[2];
    const float* att_src = (const float*)d_in[3];
    const float* att_dst = (const float*)d_in[4];
    const float* b1      = (const float*)d_in[5];
    const float* Wlin    = (const float*)d_in[6];
    const float* blin    = (const float*)d_in[7];
    float* out = (float*)d_out;

    char* ws = (char*)d_ws;
    bf16*           h       = (bf16*)ws;                        // 33,554,432 B
    float*          as_     = (float*)(ws + 33554432);          // 1 MB
    float*          ad_     = (float*)(ws + 34603008);          // 1 MB
    bf16*           Bt      = (bf16*)(ws + 35651584);           // 21,504 (pad 64K)
    unsigned int*   bccount = (unsigned int*)(ws + 35717120);   // 256*256*4 = 256 KB
    unsigned int*   cbase   = (unsigned int*)(ws + 35979264);   // 1,028 (pad 4K)
    unsigned int*   totals  = (unsigned int*)(ws + 35983360);   // 1,024 (pad 4K)
    unsigned int*   base4   = (unsigned int*)(ws + 35987456);   // 32,772 (pad 36K)
    unsigned int*   rbuf    = (unsigned int*)(ws + 36024320);   // 8,388,608
    unsigned short* eb      = (unsigned short*)(ws + 44412928); // 4,194,304

    k0C1<<<298, 256, 0, stream>>>(W1, Bt, ei, bccount);
    k1_mfma<<<NNODES_ / 64, 256, 0, stream>>>(x, Bt, att_src, att_dst, h, as_, ad_);
    kC2a<<<256, 256, 0, stream>>>(bccount, totals);
    kC2b<<<1, 256, 0, stream>>>(totals, cbase, base4);
    kC3_scatter<<<256, 256, 0, stream>>>(ei, bccount, cbase, rbuf);
    kC4_fine<<<256, 256, 0, stream>>>(rbuf, cbase, base4, eb);
    k3_graph<<<G_, 256, 0, stream>>>(eb, base4, h, as_, ad_, b1, Wlin, blin, out);
}